// Round 16
// baseline (840.142 us; speedup 1.0000x reference)
//
#include <hip/hip_runtime.h>

typedef __attribute__((ext_vector_type(8))) short short8;
typedef __attribute__((ext_vector_type(4))) float floatx4;
typedef __attribute__((ext_vector_type(8))) unsigned short ushort8;
typedef __attribute__((ext_vector_type(2))) unsigned int uint2v;

#define FOUT 18688
#define FFI  8192
#define CATW 10240   // 2048 (attn) + 8192 (swiglu)

__device__ __forceinline__ float b2f(unsigned short u){
  union { unsigned int i; float f; } v; v.i = ((unsigned int)u) << 16; return v.f;
}
__device__ __forceinline__ unsigned short f2b(float f){
  union { float f; unsigned int i; } v; v.f = f;
  unsigned int r = v.i + 0x7FFFu + ((v.i >> 16) & 1u);
  return (unsigned short)(r >> 16);
}
__device__ __forceinline__ void gld_lds16(const void* g, void* l){
  __builtin_amdgcn_global_load_lds((const __attribute__((address_space(1))) void*)g,
                                   (__attribute__((address_space(3))) void*)l, 16, 0, 0);
}

#define SCHED0() __builtin_amdgcn_sched_barrier(0)
#define BARR()   do{ SCHED0(); __builtin_amdgcn_s_barrier(); SCHED0(); }while(0)

// ---------------- LayerNorm (fp32 in) -> bf16 xn ----------------
__global__ __launch_bounds__(256) void ln_kernel(const float* __restrict__ x,
                                                 const float* __restrict__ gamma,
                                                 unsigned short* __restrict__ xn){
  int row = blockIdx.x;
  const float* xr = x + (size_t)row * 2048;
  int tid = threadIdx.x;
  float v[8]; float s = 0.f, s2 = 0.f;
#pragma unroll
  for(int i=0;i<8;i++){ float t = xr[tid + i*256]; v[i]=t; s+=t; s2+=t*t; }
#pragma unroll
  for(int off=32; off>=1; off>>=1){ s += __shfl_down(s, off, 64); s2 += __shfl_down(s2, off, 64); }
  __shared__ float red[8];
  int wv = tid>>6, ln_ = tid&63;
  if(ln_==0){ red[wv] = s; red[wv+4] = s2; }
  __syncthreads();
  s  = red[0]+red[1]+red[2]+red[3];
  s2 = red[4]+red[5]+red[6]+red[7];
  float mu  = s * (1.f/2048.f);
  float var = s2 * (1.f/2048.f) - mu*mu;
  float rstd = rsqrtf(var + 1e-5f);
#pragma unroll
  for(int i=0;i<8;i++){
    float o = (v[i]-mu)*rstd*gamma[tid + i*256];
    xn[(size_t)row*2048 + tid + i*256] = f2b(o);
  }
}

// ---------------- fp32 RxC -> bf16 CxR transpose, 64x64 tiles, vectorized ----------------
__global__ __launch_bounds__(256) void tcast64_kernel(const float* __restrict__ W,
                                                      unsigned short* __restrict__ Wt,
                                                      int C, int S, int O){
  __shared__ float t[64][65];
  int bx = blockIdx.x*64;   // col-block of W
  int by = blockIdx.y*64;   // row-block of W
  int tid = threadIdx.x;
  int r = tid>>2, cq = (tid&3)*16;
  const float* src = W + (size_t)(by + r)*C + bx + cq;
#pragma unroll
  for(int e=0;e<4;e++){
    floatx4 v = *(const floatx4*)(src + e*4);
    t[r][cq+e*4+0]=v[0]; t[r][cq+e*4+1]=v[1]; t[r][cq+e*4+2]=v[2]; t[r][cq+e*4+3]=v[3];
  }
  __syncthreads();
#pragma unroll
  for(int it=0; it<2; it++){
    int s_ = it*256 + tid;
    int c = s_>>3, j8 = s_&7;
    ushort8 o;
#pragma unroll
    for(int e=0;e<8;e++) o[e] = f2b(t[j8*8+e][c]);
    *(ushort8*)&Wt[(size_t)(bx+c)*S + O + by + j8*8] = o;
  }
}

// ---------------- V slice of proj -> Vt[b][d][n] (bf16) ----------------
__global__ void vtrans_kernel(const unsigned short* __restrict__ proj, unsigned short* __restrict__ vt){
  __shared__ unsigned short t[32][33];
  int b = blockIdx.z;
  int n0 = blockIdx.x*32, d0 = blockIdx.y*32;
  int tx = threadIdx.x, ty = threadIdx.y;
#pragma unroll
  for(int i=0;i<4;i++) t[ty+i*8][tx] = proj[(size_t)(b*2048 + n0+ty+i*8)*FOUT + 2176 + d0+tx];
  __syncthreads();
#pragma unroll
  for(int i=0;i<4;i++) vt[((size_t)b*128 + d0+ty+i*8)*2048 + n0+tx] = t[tx][ty+i*8];
}

// ---------------- RoPE table: [i<2048][j<64] {cq,sq,ck,sk}; att-scale folded into q ----------------
__global__ __launch_bounds__(256) void rope_tab_kernel(floatx4* __restrict__ tab){
  int idx = blockIdx.x*256 + threadIdx.x;   // 131072
  int i = idx >> 6, j = idx & 63;
  float fj = (float)j, fi = (float)i;
  float p = fi * powf(10000.f, -fj*(1.f/64.f));
  float c = cosf(p), s = sinf(p);
  float sv = (2.f*fj + 51.2f) * (1.f/179.2f);
  float pw = (fi - 1024.f) * (1.f/512.f);
  float sc = powf(sv, pw);
  const float att = 0.08838834764831843f;
  floatx4 o; o[0]=c*sc*att; o[1]=s*sc*att; o[2]=c/sc; o[3]=s/sc;
  tab[idx] = o;
}

// ---------------- RoPE (xpos) in-place on q heads + k, table-driven, vectorized ----------------
__global__ __launch_bounds__(256) void rope_kernel(unsigned short* __restrict__ proj,
                                                   const floatx4* __restrict__ tab){
  int row = blockIdx.x;          // b*2048 + i
  int i = row & 2047;
  int tid = threadIdx.x;
  if(tid >= 136) return;
  int slot = tid >> 3;
  int jc = (tid & 7) * 8;
  unsigned short* pr = proj + (size_t)row*FOUT + ((slot < 16) ? slot*128 : 2048) + jc;
  ushort8 x1 = *(const ushort8*)pr;
  ushort8 x2 = *(const ushort8*)(pr + 64);
  ushort8 o1, o2;
#pragma unroll
  for(int e=0; e<8; e++){
    floatx4 t = tab[i*64 + jc + e];
    float cs = (slot==16) ? t[2] : t[0];
    float ss = (slot==16) ? t[3] : t[1];
    float f1 = b2f(x1[e]);
    float f2 = b2f(x2[e]);
    o1[e] = f2b(f1*cs - f2*ss);
    o2[e] = f2b(f2*cs + f1*ss);
  }
  *(ushort8*)pr = o1;
  *(ushort8*)(pr + 64) = o2;
}

// ========= 256x128 bf16 GEMM, BK=32, 3-buf 72KiB LDS -> 2 blocks/CU (R12 retry, fixed) =========
// C(MxN) = A(MxK)*Bt(NxK)^T. 4 waves (2M x 2N), wave tile 128x64 (= proven gemm3b per-wave shape).
// Mechanism test: 2 co-resident blocks/CU, 2 waves/SIMD from DIFFERENT blocks (not barrier-
// synced) -> one block's MFMA covers the other's LDS drain / vmcnt / barrier (m114).
// R12's confound removed: gemm3b-verified swizzle chunk^((row>>1)&3) -> 2-way max (free).
// 3 buffers: stage(t+2) during tile t -> 2-tile latency budget; vmcnt(6) once per tile retires
// exactly t+1's 6 glds. Race ledger: buf[(t+2)%3]'s last readers (tile t-1) drained at the
// barrier ending t-1, before stage issues in t; vmcnt precedes barrier so buf(t+1) landed
// workgroup-wide at tile t+1 entry. Tails: t=NT-2 vmcnt(0); t=NT-1 none.
// Compiler-scheduled lgkm waits (R10 lesson: no explicit lgkmcnt, no fences around MFMA).
// MODE 0: bf16 store (8B packed). MODE 1: f32 float4 store at Cf + z*zstride.
template<int MODE>
__global__ __launch_bounds__(256, 2) void gemm2r_kernel(const unsigned short* __restrict__ A,
                                                        const unsigned short* __restrict__ Bt,
                                                        unsigned short* __restrict__ Cb,
                                                        float* __restrict__ Cf,
                                                        int N, int K, int NT, size_t zstride){
  __shared__ unsigned short lds[36864];   // 3 bufs x 12288 el (A 8192 el | B 4096 el)
  const int tid = threadIdx.x;
  const int wave = tid>>6, lane = tid&63;
  const int l15 = lane&15, l4 = lane>>4;
  const int wr = wave>>1, wc = wave&1;    // 2(M) x 2(N)
  int id = blockIdx.x;
  int cpx = (int)gridDim.x >> 3;          // gridDim.x % 8 == 0 guaranteed
  int swz = (id & 7)*cpx + (id >> 3);
  int tm = swz & 15, tn = swz >> 4;       // M/256 == 16 for both GEMMs; tn-major L2 sharing
  int kbase = (int)blockIdx.z * (NT*32);
  const unsigned short* Ab = A  + (size_t)tm*256*K + kbase;
  const unsigned short* Bb = Bt + (size_t)tn*128*K + kbase;
  if(MODE==1) Cf += (size_t)blockIdx.z * zstride;

  // staging: A 1024 slots (4/thr), B 512 slots (2/thr); LDS linear, global pre-swizzled
#define STG(t_, bufo_) do{ \
    _Pragma("unroll") for(int i_=0;i_<4;i_++){ \
      int s_ = i_*256 + tid; \
      int r_ = s_>>2, cs_ = s_&3; \
      gld_lds16(Ab + (size_t)r_*K + (t_)*32 + (cs_^((r_>>1)&3))*8, \
                &lds[(bufo_) + (i_*256 + wave*64)*8]); \
    } \
    _Pragma("unroll") for(int i_=0;i_<2;i_++){ \
      int s_ = i_*256 + tid; \
      int r_ = s_>>2, cs_ = s_&3; \
      gld_lds16(Bb + (size_t)r_*K + (t_)*32 + (cs_^((r_>>1)&3))*8, \
                &lds[(bufo_) + 8192 + (i_*256 + wave*64)*8]); \
    } \
  }while(0)

  const int fo = (l4 ^ ((l15>>1)&3))*8;       // 2-way max on 32 banks (gemm3b-verified)
  const int albase = (wr*128 + l15)*32;       // + mf*512
  const int blbase = 8192 + (wc*64 + l15)*32; // + nf*512

  floatx4 acc[8][4];
#pragma unroll
  for(int i=0;i<8;i++)
#pragma unroll
    for(int j=0;j<4;j++) acc[i][j] = (floatx4)0.f;

  STG(0, 0); STG(1, 12288);
  asm volatile("s_waitcnt vmcnt(6)" ::: "memory");
  BARR();

  int bufo = 0, sbo = 24576;
  for(int t=0; t<NT; ++t){
    short8 a_[8], b_[4];
#pragma unroll
    for(int mf=0; mf<8; mf++) a_[mf] = *(const short8*)&lds[bufo + albase + mf*512 + fo];
#pragma unroll
    for(int nf=0; nf<4; nf++) b_[nf] = *(const short8*)&lds[bufo + blbase + nf*512 + fo];
    if(t+2 < NT) STG(t+2, sbo);
    __builtin_amdgcn_s_setprio(1);
#pragma unroll
    for(int mf=0; mf<8; mf++)
#pragma unroll
      for(int nf=0; nf<4; nf++)
        acc[mf][nf] = __builtin_amdgcn_mfma_f32_16x16x32_bf16(b_[nf], a_[mf], acc[mf][nf], 0,0,0);
    __builtin_amdgcn_s_setprio(0);
    if(t+2 < NT){      asm volatile("s_waitcnt vmcnt(6)" ::: "memory"); }
    else if(t+1 < NT){ asm volatile("s_waitcnt vmcnt(0)" ::: "memory"); }
    BARR();
    bufo += 12288; if(bufo == 36864) bufo = 0;
    sbo  += 12288; if(sbo  == 36864) sbo  = 0;
  }

  // epilogue (gemm3b-proven swapped layout): lane holds 4 consecutive N-cols
  const size_t crow0 = (size_t)tm*256 + wr*128 + l15;
  const size_t ccol0 = (size_t)tn*128 + wc*64 + l4*4;
#pragma unroll
  for(int mf=0; mf<8; mf++){
    size_t row = crow0 + mf*16;
#pragma unroll
    for(int nf=0; nf<4; nf++){
      size_t col = ccol0 + nf*16;
      floatx4 v = acc[mf][nf];
      if(MODE==0){
        uint2v u;
        u[0] = (unsigned int)f2b(v[0]) | ((unsigned int)f2b(v[1])<<16);
        u[1] = (unsigned int)f2b(v[2]) | ((unsigned int)f2b(v[3])<<16);
        *(uint2v*)&Cb[row*N + col] = u;
      } else {
        *(floatx4*)&Cf[row*N + col] = v;
      }
    }
  }
}

// ---------------- partial sum: out = p0 + p1 (f32, float4) ----------------
__global__ __launch_bounds__(256) void add2_kernel(const float* __restrict__ p0,
                                                   const float* __restrict__ p1,
                                                   float* __restrict__ o, int n4){
  for(int i = blockIdx.x*256 + threadIdx.x; i < n4; i += gridDim.x*256){
    floatx4 a = ((const floatx4*)p0)[i];
    floatx4 b = ((const floatx4*)p1)[i];
    ((floatx4*)o)[i] = a + b;
  }
}

// ---------- flash causal attention, QBLK=128, 8 waves, K/V double-buffered (MQA) ----------
__global__ __launch_bounds__(512) void attn_kernel(const unsigned short* __restrict__ proj,
                                                   const unsigned short* __restrict__ vt,
                                                   unsigned short* __restrict__ ao){
  __shared__ unsigned short lK[2*8192];
  __shared__ unsigned short lV[2*8192];
  __shared__ unsigned short lP[8*1024];
  int qt = (int)gridDim.x - 1 - (int)blockIdx.x;
  int hh = blockIdx.y, b = blockIdx.z;
  int tid = threadIdx.x, wave = tid>>6, lane = tid&63;
  int l15 = lane&15, l4 = lane>>4;
  int q0 = qt*128;
  int qrow = q0 + wave*16 + l15;
  const unsigned short* qp = proj + (size_t)(b*2048 + qrow)*FOUT + hh*128 + l4*8;
  short8 qf[4];
#pragma unroll
  for(int ds=0; ds<4; ds++) qf[ds] = *(const short8*)(qp + ds*32);
  floatx4 po[8];
#pragma unroll
  for(int dt=0; dt<8; dt++) po[dt] = (floatx4)0.f;
  float mrun[4] = {-1e30f,-1e30f,-1e30f,-1e30f};
  float lrun[4] = {0.f,0.f,0.f,0.f};
  unsigned short* lPw = lP + wave*1024;
  const unsigned short* kb = proj + (size_t)(b*2048)*FOUT + 2048;
  const unsigned short* vb = vt + (size_t)b*128*2048;
  int kvmax = 2*qt + 1;

#define STAGE_K(kv_, bo_) do{ \
    _Pragma("unroll") for(int it=0; it<2; it++){ \
      int f = it*512 + tid; \
      int r = f>>4, pc = f&15; \
      int gc = pc ^ (r&7); \
      gld_lds16(kb + (size_t)((kv_)*64 + r)*FOUT + gc*8, &lK[(bo_) + (it*512 + wave*64)*8]); \
    } }while(0)
#define STAGE_V(kv_, bo_) do{ \
    _Pragma("unroll") for(int it=0; it<2; it++){ \
      int f = it*512 + tid; \
      int d = f>>3, pc = f&7; \
      int gc = pc ^ (d&7); \
      gld_lds16(vb + (size_t)d*2048 + (kv_)*64 + gc*8, &lV[(bo_) + (it*512 + wave*64)*8]); \
    } }while(0)

  STAGE_K(0, 0); STAGE_V(0, 0);

  for(int kv=0; kv<=kvmax; kv++){
    int kv0 = kv*64;
    int cb = (kv&1)*8192;
    asm volatile("s_waitcnt vmcnt(0)" ::: "memory");
    __syncthreads();
    if(kv < kvmax){ STAGE_K(kv+1, cb^8192); STAGE_V(kv+1, cb^8192); }
    floatx4 sa[4];
#pragma unroll
    for(int jt=0;jt<4;jt++) sa[jt] = (floatx4)0.f;
#pragma unroll
    for(int jt=0;jt<4;jt++){
      int krow = jt*16 + l15;
#pragma unroll
      for(int ds=0; ds<4; ds++){
        int pc = (l4 + ds*4) ^ (krow&7);
        short8 kf = *(const short8*)&lK[cb + krow*128 + pc*8];
        sa[jt] = __builtin_amdgcn_mfma_f32_16x16x32_bf16(qf[ds], kf, sa[jt], 0,0,0);
      }
    }
    float pv[4][4];
    bool diag = (kv0 + 63 > q0 + wave*16);
#pragma unroll
    for(int jt=0;jt<4;jt++){
#pragma unroll
      for(int r=0;r<4;r++){
        float s = sa[jt][r];
        if(diag && (kv0 + jt*16 + l15 > q0 + wave*16 + l4*4 + r)) s = -1e30f;
        pv[jt][r] = s;
      }
    }
    float mnew[4], corr[4];
#pragma unroll
    for(int r=0;r<4;r++){
      float mx = fmaxf(fmaxf(pv[0][r],pv[1][r]),fmaxf(pv[2][r],pv[3][r]));
      mx = fmaxf(mx, __shfl_xor(mx, 1, 64));
      mx = fmaxf(mx, __shfl_xor(mx, 2, 64));
      mx = fmaxf(mx, __shfl_xor(mx, 4, 64));
      mx = fmaxf(mx, __shfl_xor(mx, 8, 64));
      float mn = fmaxf(mrun[r], mx);
      corr[r] = __expf(mrun[r] - mn);
      mrun[r] = mn;
      mnew[r] = mn;
    }
    float rsum[4] = {0.f,0.f,0.f,0.f};
#pragma unroll
    for(int jt=0;jt<4;jt++){
#pragma unroll
      for(int r=0;r<4;r++){
        float p = __expf(pv[jt][r] - mnew[r]);
        pv[jt][r] = p;
        rsum[r] += p;
      }
    }
#pragma unroll
    for(int r=0;r<4;r++){
      float rs = rsum[r];
      rs += __shfl_xor(rs, 1, 64);
      rs += __shfl_xor(rs, 2, 64);
      rs += __shfl_xor(rs, 4, 64);
      rs += __shfl_xor(rs, 8, 64);
      lrun[r] = lrun[r]*corr[r] + rs;
    }
#pragma unroll
    for(int dt=0;dt<8;dt++){
#pragma unroll
      for(int r=0;r<4;r++) po[dt][r] *= corr[r];
    }
#pragma unroll
    for(int jt=0;jt<4;jt++){
#pragma unroll
      for(int r=0;r<4;r++){
        int i_ = l4*4 + r;
        int j = jt*16 + l15;
        int pc = (j>>3) ^ (i_&7);
        lPw[i_*64 + pc*8 + (j&7)] = f2b(pv[jt][r]);
      }
    }
    asm volatile("s_waitcnt lgkmcnt(0)" ::: "memory");
    short8 pf[2];
#pragma unroll
    for(int ks=0;ks<2;ks++){
      int pc = (l4 + ks*4) ^ (l15&7);
      pf[ks] = *(const short8*)&lPw[l15*64 + pc*8];
    }
#pragma unroll
    for(int dt=0;dt<8;dt++){
      int d = dt*16 + l15;
#pragma unroll
      for(int ks=0;ks<2;ks++){
        int pc = (ks*4 + l4) ^ (d&7);
        short8 vf = *(const short8*)&lV[cb + d*64 + pc*8];
        po[dt] = __builtin_amdgcn_mfma_f32_16x16x32_bf16(pf[ks], vf, po[dt], 0,0,0);
      }
    }
  }
#pragma unroll
  for(int r=0;r<4;r++){
    float inv = 1.f / lrun[r];
    size_t orow = (size_t)(b*2048 + q0 + wave*16 + l4*4 + r);
#pragma unroll
    for(int dt=0;dt<8;dt++){
      ao[orow*CATW + hh*128 + dt*16 + l15] = f2b(po[dt][r]*inv);
    }
  }
}

// ---------------- SwiGLU: silu(gate)*x -> cat[:, 2048:10240] ----------------
__global__ __launch_bounds__(256) void swiglu_kernel(const unsigned short* __restrict__ proj,
                                                     unsigned short* __restrict__ cat){
  size_t idx = (size_t)blockIdx.x*256 + threadIdx.x;
  int row = (int)(idx >> 10);
  int c8  = (int)(idx & 1023);
  const unsigned short* pr = proj + (size_t)row*FOUT + 2304 + c8*8;
  ushort8 xv = *(const ushort8*)pr;
  ushort8 gv = *(const ushort8*)(pr + FFI);
  ushort8 ov;
#pragma unroll
  for(int e=0;e<8;e++){
    float xf = b2f(xv[e]);
    float gf = b2f(gv[e]);
    float sg = gf / (1.f + __expf(-gf));
    ov[e] = f2b(sg*xf);
  }
  *(ushort8*)(cat + (size_t)row*CATW + 2048 + c8*8) = ov;
}

extern "C" void kernel_launch(void* const* d_in, const int* in_sizes, int n_in,
                              void* d_out, int out_size, void* d_ws, size_t ws_size,
                              hipStream_t stream){
  const float* x     = (const float*)d_in[0];
  const float* gamma = (const float*)d_in[1];
  const float* Wf    = (const float*)d_in[2];
  const float* Wa    = (const float*)d_in[3];
  const float* Wff   = (const float*)d_in[4];
  float* out = (float*)d_out;

  char* p = (char*)d_ws;
  unsigned short* xn    = (unsigned short*)p;  p += (size_t)4096*2048*2;
  unsigned short* WfT   = (unsigned short*)p;  p += (size_t)18688*2048*2;
  unsigned short* proj  = (unsigned short*)p;  p += (size_t)4096*18688*2;
  unsigned short* BtCat = (unsigned short*)p;  p += (size_t)2048*CATW*2;
  unsigned short* cat   = (unsigned short*)p;  p += (size_t)4096*CATW*2;
  unsigned short* vtb   = (unsigned short*)p;  p += (size_t)2*128*2048*2;
  floatx4*        rtab  = (floatx4*)p;         p += (size_t)2048*64*16;
  float* part = (float*)d_ws;  // aliases xn+WfT (64 MB <= 92.5 MB, both dead by then)

  ln_kernel<<<4096, 256, 0, stream>>>(x, gamma, xn);
  rope_tab_kernel<<<512, 256, 0, stream>>>(rtab);
  tcast64_kernel<<<dim3(292,32),  256, 0, stream>>>(Wf,  WfT,   18688, 2048, 0);
  tcast64_kernel<<<dim3(32,32),   256, 0, stream>>>(Wa,  BtCat, 2048,  CATW, 0);
  tcast64_kernel<<<dim3(32,128),  256, 0, stream>>>(Wff, BtCat, 2048,  CATW, 2048);
  // GEMM1: proj = xn @ WfT^T  (4096 x 18688 x 2048): 16 x 146 tiles of 256x128, NT=64
  gemm2r_kernel<0><<<dim3(2336,1,1), 256, 0, stream>>>(xn, WfT, proj, nullptr, 18688, 2048, 64, 0);
  rope_kernel<<<4096, 256, 0, stream>>>(proj, rtab);
  vtrans_kernel<<<dim3(64,4,2), dim3(32,8), 0, stream>>>(proj, vtb);
  attn_kernel<<<dim3(16,16,2), 512, 0, stream>>>(proj, vtb, cat);
  swiglu_kernel<<<16384, 256, 0, stream>>>(proj, cat);
  // GEMM23 fused: part[z] = cat[:, zK] @ BtCat[:, zK]^T (4096 x 2048 x 10240, split-K=2,
  // 16 x 16 tiles of 256x128 per z -> 512 blocks = 2/CU co-resident), NT=160
  gemm2r_kernel<1><<<dim3(256,1,2), 256, 0, stream>>>(cat, BtCat, nullptr, part, 2048, 10240, 160,
                                                      (size_t)4096*2048);
  add2_kernel<<<2048, 256, 0, stream>>>(part, part + (size_t)4096*2048, out, 2097152);
}

// Round 17
// 734.215 us; speedup vs baseline: 1.1443x; 1.1443x over previous
//
#include <hip/hip_runtime.h>

typedef __attribute__((ext_vector_type(8))) short short8;
typedef __attribute__((ext_vector_type(4))) float floatx4;
typedef __attribute__((ext_vector_type(8))) unsigned short ushort8;

#define FOUT 18688
#define FFI  8192
#define CATW 10240   // 2048 (attn) + 8192 (swiglu)

__device__ __forceinline__ float b2f(unsigned short u){
  union { unsigned int i; float f; } v; v.i = ((unsigned int)u) << 16; return v.f;
}
__device__ __forceinline__ unsigned short f2b(float f){
  union { float f; unsigned int i; } v; v.f = f;
  unsigned int r = v.i + 0x7FFFu + ((v.i >> 16) & 1u);
  return (unsigned short)(r >> 16);
}
__device__ __forceinline__ void gld_lds16(const void* g, void* l){
  __builtin_amdgcn_global_load_lds((const __attribute__((address_space(1))) void*)g,
                                   (__attribute__((address_space(3))) void*)l, 16, 0, 0);
}

#define SCHED0() __builtin_amdgcn_sched_barrier(0)
#define BARR()   do{ SCHED0(); __builtin_amdgcn_s_barrier(); SCHED0(); }while(0)

// ---------------- LayerNorm (fp32 in) -> bf16 xn ----------------
__global__ __launch_bounds__(256) void ln_kernel(const float* __restrict__ x,
                                                 const float* __restrict__ gamma,
                                                 unsigned short* __restrict__ xn){
  int row = blockIdx.x;
  const float* xr = x + (size_t)row * 2048;
  int tid = threadIdx.x;
  float v[8]; float s = 0.f, s2 = 0.f;
#pragma unroll
  for(int i=0;i<8;i++){ float t = xr[tid + i*256]; v[i]=t; s+=t; s2+=t*t; }
#pragma unroll
  for(int off=32; off>=1; off>>=1){ s += __shfl_down(s, off, 64); s2 += __shfl_down(s2, off, 64); }
  __shared__ float red[8];
  int wv = tid>>6, ln_ = tid&63;
  if(ln_==0){ red[wv] = s; red[wv+4] = s2; }
  __syncthreads();
  s  = red[0]+red[1]+red[2]+red[3];
  s2 = red[4]+red[5]+red[6]+red[7];
  float mu  = s * (1.f/2048.f);
  float var = s2 * (1.f/2048.f) - mu*mu;
  float rstd = rsqrtf(var + 1e-5f);
#pragma unroll
  for(int i=0;i<8;i++){
    float o = (v[i]-mu)*rstd*gamma[tid + i*256];
    xn[(size_t)row*2048 + tid + i*256] = f2b(o);
  }
}

// ---------------- fp32 RxC -> bf16 CxR transpose, 64x64 tiles, vectorized ----------------
__global__ __launch_bounds__(256) void tcast64_kernel(const float* __restrict__ W,
                                                      unsigned short* __restrict__ Wt,
                                                      int C, int S, int O){
  __shared__ float t[64][65];
  int bx = blockIdx.x*64;   // col-block of W
  int by = blockIdx.y*64;   // row-block of W
  int tid = threadIdx.x;
  int r = tid>>2, cq = (tid&3)*16;
  const float* src = W + (size_t)(by + r)*C + bx + cq;
#pragma unroll
  for(int e=0;e<4;e++){
    floatx4 v = *(const floatx4*)(src + e*4);
    t[r][cq+e*4+0]=v[0]; t[r][cq+e*4+1]=v[1]; t[r][cq+e*4+2]=v[2]; t[r][cq+e*4+3]=v[3];
  }
  __syncthreads();
#pragma unroll
  for(int it=0; it<2; it++){
    int s_ = it*256 + tid;
    int c = s_>>3, j8 = s_&7;
    ushort8 o;
#pragma unroll
    for(int e=0;e<8;e++) o[e] = f2b(t[j8*8+e][c]);
    *(ushort8*)&Wt[(size_t)(bx+c)*S + O + by + j8*8] = o;
  }
}

// ---------------- V slice of proj -> Vt[b][d][n] (bf16) ----------------
__global__ void vtrans_kernel(const unsigned short* __restrict__ proj, unsigned short* __restrict__ vt){
  __shared__ unsigned short t[32][33];
  int b = blockIdx.z;
  int n0 = blockIdx.x*32, d0 = blockIdx.y*32;
  int tx = threadIdx.x, ty = threadIdx.y;
#pragma unroll
  for(int i=0;i<4;i++) t[ty+i*8][tx] = proj[(size_t)(b*2048 + n0+ty+i*8)*FOUT + 2176 + d0+tx];
  __syncthreads();
#pragma unroll
  for(int i=0;i<4;i++) vt[((size_t)b*128 + d0+ty+i*8)*2048 + n0+tx] = t[tx][ty+i*8];
}

// ---------------- RoPE table: [i<2048][j<64] {cq,sq,ck,sk}; att-scale folded into q ----------------
__global__ __launch_bounds__(256) void rope_tab_kernel(floatx4* __restrict__ tab){
  int idx = blockIdx.x*256 + threadIdx.x;   // 131072
  int i = idx >> 6, j = idx & 63;
  float fj = (float)j, fi = (float)i;
  float p = fi * powf(10000.f, -fj*(1.f/64.f));
  float c = cosf(p), s = sinf(p);
  float sv = (2.f*fj + 51.2f) * (1.f/179.2f);
  float pw = (fi - 1024.f) * (1.f/512.f);
  float sc = powf(sv, pw);
  const float att = 0.08838834764831843f;
  floatx4 o; o[0]=c*sc*att; o[1]=s*sc*att; o[2]=c/sc; o[3]=s/sc;
  tab[idx] = o;
}

// ---------------- RoPE (xpos) in-place on q heads + k, table-driven ----------------
__global__ __launch_bounds__(256) void rope_kernel(unsigned short* __restrict__ proj,
                                                   const floatx4* __restrict__ tab){
  int row = blockIdx.x;          // b*2048 + i
  int i = row & 2047;
  unsigned short* pr = proj + (size_t)row*FOUT;
  for(int item = threadIdx.x; item < 17*64; item += 256){
    int slot = item >> 6;        // 0..15 = q head, 16 = k
    int j = item & 63;
    floatx4 t = tab[i*64 + j];
    float cs = (slot==16) ? t[2] : t[0];
    float ss = (slot==16) ? t[3] : t[1];
    int colbase = (slot<16) ? slot*128 : 2048;
    float x1 = b2f(pr[colbase+j]);
    float x2 = b2f(pr[colbase+j+64]);
    pr[colbase+j]    = f2b(x1*cs - x2*ss);
    pr[colbase+j+64] = f2b(x2*cs + x1*ss);
  }
}

// ================= 256x256 bf16 GEMM — compiler-scheduled phases (R10-proven, 306us GEMM1) ===
// C(MxN) = A(MxK)*Bt(NxK)^T. BK=64, 8 waves (2M x 4N), 128KiB LDS dbuf, tn-major tiling.
// No explicit lgkmcnt: compiler emits fine-grained waits so the first MFMA starts as soon as
// ITS operands land (m97 mechanism). One barrier per phase. Stage slots: P1 A-h1(t+1) |
// P2 B-h0(t+2) | P3 B-h1(t+2) | P4 A-h0(t+2). vm FIFO at P4: 14 outstanding, vmcnt(6)
// retires the 8 oldest = ALL of buf(t+1). Tails: t=NT-2 waits vmcnt(0); last tile none.
// MODE 0: bf16 store. MODE 1: f32 store at Cf + z*zstride (split-K partials, kbase=z*NT*64).
template<int MODE>
__global__ __launch_bounds__(512, 2) void gemm8p_kernel(const unsigned short* __restrict__ A,
                                                        const unsigned short* __restrict__ Bt,
                                                        unsigned short* __restrict__ Cb,
                                                        float* __restrict__ Cf,
                                                        int N, int K, int NT, size_t zstride){
  __shared__ unsigned short lds[65536];   // [buf][A 16384 el | B 16384 el]
  const int tid = threadIdx.x;
  const int wave = tid>>6, lane = tid&63;
  const int l15 = lane&15, l4 = lane>>4;
  const int wr = wave>>2, wc = wave&3;    // 2(M) x 4(N)
  int id = blockIdx.x;
  int cpx = (int)gridDim.x >> 3;          // gridDim.x % 8 == 0 guaranteed
  int swz = (id & 7)*cpx + (id >> 3);
  int tm = swz & 15, tn = swz >> 4;
  int kbase = (int)blockIdx.z * (NT*64);
  const unsigned short* Ab = A  + (size_t)tm*256*K + kbase;
  const unsigned short* Bb = Bt + (size_t)tn*256*K + kbase;
  if(MODE==1) Cf += (size_t)blockIdx.z * zstride;

  const int r0 = tid>>3;
  const int colc = ((tid&7) ^ (r0&7))*8;  // pre-swizzled global chunk
  const int dstw = wave*512;

#define STAGE(t_, h_, isB_) do{ \
    const unsigned short* g_ = (isB_) ? Bb : Ab; \
    int db_ = (((t_)&1)<<15) + ((isB_)<<14) + ((h_)<<13) + dstw; \
    gld_lds16(g_ + (size_t)((h_)*128 + r0)*K + (t_)*64 + colc, &lds[db_]); \
    gld_lds16(g_ + (size_t)((h_)*128 + r0 + 64)*K + (t_)*64 + colc, &lds[db_ + 4096]); \
  }while(0)

  const int sw8 = l15&7;
  const int fo0 = ((l4    )^sw8)*8;   // k-half 0
  const int fo1 = ((l4 + 4)^sw8)*8;   // k-half 1
  const int albase = (wr*128 + l15)*64;
  const int blbase = 16384 + (wc*64 + l15)*64;

#define RD_A4(arr_, buf_, mh_, fo_) do{ \
  _Pragma("unroll") for(int mf=0; mf<4; mf++) \
    arr_[mf] = *(const short8*)&lds[(buf_) + albase + (mh_)*4096 + mf*1024 + (fo_)]; }while(0)
#define RD_B4(arr_, buf_, fo_) do{ \
  _Pragma("unroll") for(int nf=0; nf<4; nf++) \
    arr_[nf] = *(const short8*)&lds[(buf_) + blbase + nf*1024 + (fo_)]; }while(0)
#define MFMA_P(aarr_, barr_, mh_) do{ \
  _Pragma("unroll") for(int mf=0; mf<4; mf++) \
  _Pragma("unroll") for(int nf=0; nf<4; nf++) \
    acc[(mh_)*4+mf][nf] = __builtin_amdgcn_mfma_f32_16x16x32_bf16( \
      aarr_[mf], barr_[nf], acc[(mh_)*4+mf][nf], 0,0,0); }while(0)

  floatx4 acc[8][4];
#pragma unroll
  for(int i=0;i<8;i++)
#pragma unroll
    for(int j=0;j<4;j++) acc[i][j] = (floatx4)0.f;

  STAGE(0,0,0); STAGE(0,1,0); STAGE(0,0,1); STAGE(0,1,1);
  STAGE(1,0,1); STAGE(1,1,1); STAGE(1,0,0);
  asm volatile("s_waitcnt vmcnt(6)" ::: "memory");
  BARR();

  short8 a00_[4], a01_[4], a10_[4], a11_[4], b0_[4], b1_[4];
  for(int t=0; t<NT; ++t){
    const int bufo = (t&1)<<15;
    // ---- P1 (m0,k0): reads a00+b0; stage A-h1(t+1); MFMA; BAR ----
    RD_A4(a00_, bufo, 0, fo0);
    RD_B4(b0_,  bufo, fo0);
    if(t+1 < NT) STAGE(t+1,1,0);
    __builtin_amdgcn_s_setprio(1);
    MFMA_P(a00_, b0_, 0);
    __builtin_amdgcn_s_setprio(0);
    BARR();
    // ---- P2 (m0,k1): reads a01+b1; stage B-h0(t+2); MFMA; BAR ----
    RD_A4(a01_, bufo, 0, fo1);
    RD_B4(b1_,  bufo, fo1);
    if(t+2 < NT) STAGE(t+2,0,1);
    __builtin_amdgcn_s_setprio(1);
    MFMA_P(a01_, b1_, 0);
    __builtin_amdgcn_s_setprio(0);
    BARR();
    // ---- P3 (m1,k0): reads a10, b0 reused; stage B-h1(t+2); MFMA; BAR ----
    RD_A4(a10_, bufo, 1, fo0);
    if(t+2 < NT) STAGE(t+2,1,1);
    __builtin_amdgcn_s_setprio(1);
    MFMA_P(a10_, b0_, 1);
    __builtin_amdgcn_s_setprio(0);
    BARR();
    // ---- P4 (m1,k1): reads a11, b1 reused; stage A-h0(t+2); vmcnt gate; MFMA; BAR ----
    RD_A4(a11_, bufo, 1, fo1);
    if(t+2 < NT){
      STAGE(t+2,0,0);
      asm volatile("s_waitcnt vmcnt(6)" ::: "memory");
    } else if(t+1 < NT){
      asm volatile("s_waitcnt vmcnt(0)" ::: "memory");
    }
    __builtin_amdgcn_s_setprio(1);
    MFMA_P(a11_, b1_, 1);
    __builtin_amdgcn_s_setprio(0);
    BARR();
  }

#pragma unroll
  for(int m=0;m<8;m++){
#pragma unroll
    for(int n=0;n<4;n++){
#pragma unroll
      for(int r=0;r<4;r++){
        size_t row = (size_t)tm*256 + wr*128 + (m>>2)*64 + (m&3)*16 + l4*4 + r;
        size_t col = (size_t)tn*256 + wc*64 + n*16 + l15;
        float v = acc[m][n][r];
        if(MODE==0)      Cb[row*N + col] = f2b(v);
        else             Cf[row*N + col] = v;
      }
    }
  }
}

// ---------------- partial sum: out = p0 + p1 (f32, float4) ----------------
__global__ __launch_bounds__(256) void add2_kernel(const float* __restrict__ p0,
                                                   const float* __restrict__ p1,
                                                   float* __restrict__ o, int n4){
  for(int i = blockIdx.x*256 + threadIdx.x; i < n4; i += gridDim.x*256){
    floatx4 a = ((const floatx4*)p0)[i];
    floatx4 b = ((const floatx4*)p1)[i];
    ((floatx4*)o)[i] = a + b;
  }
}

// ---------- flash causal attention, QBLK=128, 8 waves, K/V double-buffered (MQA) ----------
__global__ __launch_bounds__(512) void attn_kernel(const unsigned short* __restrict__ proj,
                                                   const unsigned short* __restrict__ vt,
                                                   unsigned short* __restrict__ ao){
  __shared__ unsigned short lK[2*8192];   // 2 x 16KB [key][d] chunk-swizzled
  __shared__ unsigned short lV[2*8192];   // 2 x 16KB [d][key] chunk-swizzled
  __shared__ unsigned short lP[8*1024];   // 16KB per-wave P
  int qt = (int)gridDim.x - 1 - (int)blockIdx.x;
  int hh = blockIdx.y, b = blockIdx.z;
  int tid = threadIdx.x, wave = tid>>6, lane = tid&63;
  int l15 = lane&15, l4 = lane>>4;
  int q0 = qt*128;
  int qrow = q0 + wave*16 + l15;
  const unsigned short* qp = proj + (size_t)(b*2048 + qrow)*FOUT + hh*128 + l4*8;
  short8 qf[4];
#pragma unroll
  for(int ds=0; ds<4; ds++) qf[ds] = *(const short8*)(qp + ds*32);
  floatx4 po[8];
#pragma unroll
  for(int dt=0; dt<8; dt++) po[dt] = (floatx4)0.f;
  float mrun[4] = {-1e30f,-1e30f,-1e30f,-1e30f};
  float lrun[4] = {0.f,0.f,0.f,0.f};
  unsigned short* lPw = lP + wave*1024;
  const unsigned short* kb = proj + (size_t)(b*2048)*FOUT + 2048;
  const unsigned short* vb = vt + (size_t)b*128*2048;
  int kvmax = 2*qt + 1;

#define STAGE_K(kv_, bo_) do{ \
    _Pragma("unroll") for(int it=0; it<2; it++){ \
      int f = it*512 + tid; \
      int r = f>>4, pc = f&15; \
      int gc = pc ^ (r&7); \
      gld_lds16(kb + (size_t)((kv_)*64 + r)*FOUT + gc*8, &lK[(bo_) + (it*512 + wave*64)*8]); \
    } }while(0)
#define STAGE_V(kv_, bo_) do{ \
    _Pragma("unroll") for(int it=0; it<2; it++){ \
      int f = it*512 + tid; \
      int d = f>>3, pc = f&7; \
      int gc = pc ^ (d&7); \
      gld_lds16(vb + (size_t)d*2048 + (kv_)*64 + gc*8, &lV[(bo_) + (it*512 + wave*64)*8]); \
    } }while(0)

  STAGE_K(0, 0); STAGE_V(0, 0);

  for(int kv=0; kv<=kvmax; kv++){
    int kv0 = kv*64;
    int cb = (kv&1)*8192;
    asm volatile("s_waitcnt vmcnt(0)" ::: "memory");
    __syncthreads();
    if(kv < kvmax){ STAGE_K(kv+1, cb^8192); STAGE_V(kv+1, cb^8192); }
    floatx4 sa[4];
#pragma unroll
    for(int jt=0;jt<4;jt++) sa[jt] = (floatx4)0.f;
#pragma unroll
    for(int jt=0;jt<4;jt++){
      int krow = jt*16 + l15;
#pragma unroll
      for(int ds=0; ds<4; ds++){
        int pc = (l4 + ds*4) ^ (krow&7);
        short8 kf = *(const short8*)&lK[cb + krow*128 + pc*8];
        sa[jt] = __builtin_amdgcn_mfma_f32_16x16x32_bf16(qf[ds], kf, sa[jt], 0,0,0);
      }
    }
    float pv[4][4];
    bool diag = (kv0 + 63 > q0 + wave*16);
#pragma unroll
    for(int jt=0;jt<4;jt++){
#pragma unroll
      for(int r=0;r<4;r++){
        float s = sa[jt][r];
        if(diag && (kv0 + jt*16 + l15 > q0 + wave*16 + l4*4 + r)) s = -1e30f;
        pv[jt][r] = s;
      }
    }
    float mnew[4], corr[4];
#pragma unroll
    for(int r=0;r<4;r++){
      float mx = fmaxf(fmaxf(pv[0][r],pv[1][r]),fmaxf(pv[2][r],pv[3][r]));
      mx = fmaxf(mx, __shfl_xor(mx, 1, 64));
      mx = fmaxf(mx, __shfl_xor(mx, 2, 64));
      mx = fmaxf(mx, __shfl_xor(mx, 4, 64));
      mx = fmaxf(mx, __shfl_xor(mx, 8, 64));
      float mn = fmaxf(mrun[r], mx);
      corr[r] = __expf(mrun[r] - mn);
      mrun[r] = mn;
      mnew[r] = mn;
    }
    float rsum[4] = {0.f,0.f,0.f,0.f};
#pragma unroll
    for(int jt=0;jt<4;jt++){
#pragma unroll
      for(int r=0;r<4;r++){
        float p = __expf(pv[jt][r] - mnew[r]);
        pv[jt][r] = p;
        rsum[r] += p;
      }
    }
#pragma unroll
    for(int r=0;r<4;r++){
      float rs = rsum[r];
      rs += __shfl_xor(rs, 1, 64);
      rs += __shfl_xor(rs, 2, 64);
      rs += __shfl_xor(rs, 4, 64);
      rs += __shfl_xor(rs, 8, 64);
      lrun[r] = lrun[r]*corr[r] + rs;
    }
#pragma unroll
    for(int dt=0;dt<8;dt++){
#pragma unroll
      for(int r=0;r<4;r++) po[dt][r] *= corr[r];
    }
#pragma unroll
    for(int jt=0;jt<4;jt++){
#pragma unroll
      for(int r=0;r<4;r++){
        int i_ = l4*4 + r;
        int j = jt*16 + l15;
        int pc = (j>>3) ^ (i_&7);
        lPw[i_*64 + pc*8 + (j&7)] = f2b(pv[jt][r]);
      }
    }
    asm volatile("s_waitcnt lgkmcnt(0)" ::: "memory");
    short8 pf[2];
#pragma unroll
    for(int ks=0;ks<2;ks++){
      int pc = (l4 + ks*4) ^ (l15&7);
      pf[ks] = *(const short8*)&lPw[l15*64 + pc*8];
    }
#pragma unroll
    for(int dt=0;dt<8;dt++){
      int d = dt*16 + l15;
#pragma unroll
      for(int ks=0;ks<2;ks++){
        int pc = (ks*4 + l4) ^ (d&7);
        short8 vf = *(const short8*)&lV[cb + d*64 + pc*8];
        po[dt] = __builtin_amdgcn_mfma_f32_16x16x32_bf16(pf[ks], vf, po[dt], 0,0,0);
      }
    }
  }
#pragma unroll
  for(int r=0;r<4;r++){
    float inv = 1.f / lrun[r];
    size_t orow = (size_t)(b*2048 + q0 + wave*16 + l4*4 + r);
#pragma unroll
    for(int dt=0;dt<8;dt++){
      ao[orow*CATW + hh*128 + dt*16 + l15] = f2b(po[dt][r]*inv);
    }
  }
}

// ---------------- SwiGLU: silu(gate)*x -> cat[:, 2048:10240] ----------------
__global__ __launch_bounds__(256) void swiglu_kernel(const unsigned short* __restrict__ proj,
                                                     unsigned short* __restrict__ cat){
  size_t idx = (size_t)blockIdx.x*256 + threadIdx.x;
  int row = (int)(idx >> 10);
  int c8  = (int)(idx & 1023);
  const unsigned short* pr = proj + (size_t)row*FOUT + 2304 + c8*8;
  ushort8 xv = *(const ushort8*)pr;
  ushort8 gv = *(const ushort8*)(pr + FFI);
  ushort8 ov;
#pragma unroll
  for(int e=0;e<8;e++){
    float xf = b2f(xv[e]);
    float gf = b2f(gv[e]);
    float sg = gf / (1.f + __expf(-gf));
    ov[e] = f2b(sg*xf);
  }
  *(ushort8*)(cat + (size_t)row*CATW + 2048 + c8*8) = ov;
}

extern "C" void kernel_launch(void* const* d_in, const int* in_sizes, int n_in,
                              void* d_out, int out_size, void* d_ws, size_t ws_size,
                              hipStream_t stream){
  const float* x     = (const float*)d_in[0];
  const float* gamma = (const float*)d_in[1];
  const float* Wf    = (const float*)d_in[2];
  const float* Wa    = (const float*)d_in[3];
  const float* Wff   = (const float*)d_in[4];
  float* out = (float*)d_out;

  char* p = (char*)d_ws;
  unsigned short* xn    = (unsigned short*)p;  p += (size_t)4096*2048*2;
  unsigned short* WfT   = (unsigned short*)p;  p += (size_t)18688*2048*2;
  unsigned short* proj  = (unsigned short*)p;  p += (size_t)4096*18688*2;
  unsigned short* BtCat = (unsigned short*)p;  p += (size_t)2048*CATW*2;
  unsigned short* cat   = (unsigned short*)p;  p += (size_t)4096*CATW*2;
  unsigned short* vtb   = (unsigned short*)p;  p += (size_t)2*128*2048*2;
  floatx4*        rtab  = (floatx4*)p;         p += (size_t)2048*64*16;
  float* part = (float*)d_ws;  // aliases xn+WfT (64 MB <= 92.5 MB, both dead by then)

  ln_kernel<<<4096, 256, 0, stream>>>(x, gamma, xn);
  rope_tab_kernel<<<512, 256, 0, stream>>>(rtab);
  tcast64_kernel<<<dim3(292,32),  256, 0, stream>>>(Wf,  WfT,   18688, 2048, 0);
  tcast64_kernel<<<dim3(32,32),   256, 0, stream>>>(Wa,  BtCat, 2048,  CATW, 0);
  tcast64_kernel<<<dim3(32,128),  256, 0, stream>>>(Wff, BtCat, 2048,  CATW, 2048);
  // GEMM1: proj = xn @ WfT^T   (4096 x 18688 x 2048), tn-major tiling
  gemm8p_kernel<0><<<dim3(1168,1,1), 512, 0, stream>>>(xn, WfT, proj, nullptr, 18688, 2048, 32, 0);
  rope_kernel<<<4096, 256, 0, stream>>>(proj, rtab);
  vtrans_kernel<<<dim3(64,4,2), dim3(32,8), 0, stream>>>(proj, vtb);
  attn_kernel<<<dim3(16,16,2), 512, 0, stream>>>(proj, vtb, cat);
  swiglu_kernel<<<16384, 256, 0, stream>>>(proj, cat);
  // GEMM23 fused: part[z] = cat[:, zK] @ BtCat[:, zK]^T  (4096 x 2048 x 10240, split-K=2)
  gemm8p_kernel<1><<<dim3(128,1,2), 512, 0, stream>>>(cat, BtCat, nullptr, part, 2048, 10240, 80,
                                                      (size_t)4096*2048);
  add2_kernel<<<2048, 256, 0, stream>>>(part, part + (size_t)4096*2048, out, 2097152);
}

// Round 18
// 719.894 us; speedup vs baseline: 1.1670x; 1.0199x over previous
//
#include <hip/hip_runtime.h>

typedef __attribute__((ext_vector_type(8))) short short8;
typedef __attribute__((ext_vector_type(4))) float floatx4;
typedef __attribute__((ext_vector_type(8))) unsigned short ushort8;

#define FOUT 18688
#define FFI  8192
#define CATW 10240   // 2048 (attn) + 8192 (swiglu)

__device__ __forceinline__ float b2f(unsigned short u){
  union { unsigned int i; float f; } v; v.i = ((unsigned int)u) << 16; return v.f;
}
__device__ __forceinline__ unsigned short f2b(float f){
  union { float f; unsigned int i; } v; v.f = f;
  unsigned int r = v.i + 0x7FFFu + ((v.i >> 16) & 1u);
  return (unsigned short)(r >> 16);
}
__device__ __forceinline__ void gld_lds16(const void* g, void* l){
  __builtin_amdgcn_global_load_lds((const __attribute__((address_space(1))) void*)g,
                                   (__attribute__((address_space(3))) void*)l, 16, 0, 0);
}

#define SCHED0() __builtin_amdgcn_sched_barrier(0)
#define BARR()   do{ SCHED0(); __builtin_amdgcn_s_barrier(); SCHED0(); }while(0)

// ---------------- LayerNorm (fp32 in) -> bf16 xn ----------------
__global__ __launch_bounds__(256) void ln_kernel(const float* __restrict__ x,
                                                 const float* __restrict__ gamma,
                                                 unsigned short* __restrict__ xn){
  int row = blockIdx.x;
  const float* xr = x + (size_t)row * 2048;
  int tid = threadIdx.x;
  float v[8]; float s = 0.f, s2 = 0.f;
#pragma unroll
  for(int i=0;i<8;i++){ float t = xr[tid + i*256]; v[i]=t; s+=t; s2+=t*t; }
#pragma unroll
  for(int off=32; off>=1; off>>=1){ s += __shfl_down(s, off, 64); s2 += __shfl_down(s2, off, 64); }
  __shared__ float red[8];
  int wv = tid>>6, ln_ = tid&63;
  if(ln_==0){ red[wv] = s; red[wv+4] = s2; }
  __syncthreads();
  s  = red[0]+red[1]+red[2]+red[3];
  s2 = red[4]+red[5]+red[6]+red[7];
  float mu  = s * (1.f/2048.f);
  float var = s2 * (1.f/2048.f) - mu*mu;
  float rstd = rsqrtf(var + 1e-5f);
#pragma unroll
  for(int i=0;i<8;i++){
    float o = (v[i]-mu)*rstd*gamma[tid + i*256];
    xn[(size_t)row*2048 + tid + i*256] = f2b(o);
  }
}

// ---------------- fp32 RxC -> bf16 CxR transpose, 64x64 tiles, vectorized ----------------
__global__ __launch_bounds__(256) void tcast64_kernel(const float* __restrict__ W,
                                                      unsigned short* __restrict__ Wt,
                                                      int C, int S, int O){
  __shared__ float t[64][65];
  int bx = blockIdx.x*64;   // col-block of W
  int by = blockIdx.y*64;   // row-block of W
  int tid = threadIdx.x;
  int r = tid>>2, cq = (tid&3)*16;
  const float* src = W + (size_t)(by + r)*C + bx + cq;
#pragma unroll
  for(int e=0;e<4;e++){
    floatx4 v = *(const floatx4*)(src + e*4);
    t[r][cq+e*4+0]=v[0]; t[r][cq+e*4+1]=v[1]; t[r][cq+e*4+2]=v[2]; t[r][cq+e*4+3]=v[3];
  }
  __syncthreads();
#pragma unroll
  for(int it=0; it<2; it++){
    int s_ = it*256 + tid;
    int c = s_>>3, j8 = s_&7;
    ushort8 o;
#pragma unroll
    for(int e=0;e<8;e++) o[e] = f2b(t[j8*8+e][c]);
    *(ushort8*)&Wt[(size_t)(bx+c)*S + O + by + j8*8] = o;
  }
}

// ---------------- V slice of proj -> Vt[b][d][n] (bf16) ----------------
__global__ void vtrans_kernel(const unsigned short* __restrict__ proj, unsigned short* __restrict__ vt){
  __shared__ unsigned short t[32][33];
  int b = blockIdx.z;
  int n0 = blockIdx.x*32, d0 = blockIdx.y*32;
  int tx = threadIdx.x, ty = threadIdx.y;
#pragma unroll
  for(int i=0;i<4;i++) t[ty+i*8][tx] = proj[(size_t)(b*2048 + n0+ty+i*8)*FOUT + 2176 + d0+tx];
  __syncthreads();
#pragma unroll
  for(int i=0;i<4;i++) vt[((size_t)b*128 + d0+ty+i*8)*2048 + n0+tx] = t[tx][ty+i*8];
}

// ---------------- RoPE table: [i<2048][j<64] {cq,sq,ck,sk}; att-scale folded into q ----------------
__global__ __launch_bounds__(256) void rope_tab_kernel(floatx4* __restrict__ tab){
  int idx = blockIdx.x*256 + threadIdx.x;   // 131072
  int i = idx >> 6, j = idx & 63;
  float fj = (float)j, fi = (float)i;
  float p = fi * powf(10000.f, -fj*(1.f/64.f));
  float c = cosf(p), s = sinf(p);
  float sv = (2.f*fj + 51.2f) * (1.f/179.2f);
  float pw = (fi - 1024.f) * (1.f/512.f);
  float sc = powf(sv, pw);
  const float att = 0.08838834764831843f;
  floatx4 o; o[0]=c*sc*att; o[1]=s*sc*att; o[2]=c/sc; o[3]=s/sc;
  tab[idx] = o;
}

// ---------------- RoPE (xpos) in-place on q heads + k, table-driven ----------------
__global__ __launch_bounds__(256) void rope_kernel(unsigned short* __restrict__ proj,
                                                   const floatx4* __restrict__ tab){
  int row = blockIdx.x;          // b*2048 + i
  int i = row & 2047;
  unsigned short* pr = proj + (size_t)row*FOUT;
  for(int item = threadIdx.x; item < 17*64; item += 256){
    int slot = item >> 6;        // 0..15 = q head, 16 = k
    int j = item & 63;
    floatx4 t = tab[i*64 + j];
    float cs = (slot==16) ? t[2] : t[0];
    float ss = (slot==16) ? t[3] : t[1];
    int colbase = (slot<16) ? slot*128 : 2048;
    float x1 = b2f(pr[colbase+j]);
    float x2 = b2f(pr[colbase+j+64]);
    pr[colbase+j]    = f2b(x1*cs - x2*ss);
    pr[colbase+j+64] = f2b(x2*cs + x1*ss);
  }
}

// ================= 256x256 bf16 GEMM — compiler-scheduled phases (R10-proven, 306us GEMM1) ===
// C(MxN) = A(MxK)*Bt(NxK)^T. BK=64, 8 waves (2M x 4N), 128KiB LDS dbuf.
// MODE 0: bf16 store, tn-major XCD tiling. MODE 1: f32 split-K partial via blockIdx.z.
// MODE 2: f32 split-K partial with z FOLDED into blockIdx.x (z = id&1): since XCD = id%8,
//   even XCDs handle only z=0 and odd only z=1 -> per-XCD A working set halves (84->42MB).
//   rid=id>>1, tn=rid&7, tm=rid>>3 (bijective over 16x8x2).
template<int MODE>
__global__ __launch_bounds__(512, 2) void gemm8p_kernel(const unsigned short* __restrict__ A,
                                                        const unsigned short* __restrict__ Bt,
                                                        unsigned short* __restrict__ Cb,
                                                        float* __restrict__ Cf,
                                                        int N, int K, int NT, size_t zstride){
  __shared__ unsigned short lds[65536];   // [buf][A 16384 el | B 16384 el]
  const int tid = threadIdx.x;
  const int wave = tid>>6, lane = tid&63;
  const int l15 = lane&15, l4 = lane>>4;
  const int wr = wave>>2, wc = wave&3;    // 2(M) x 4(N)
  int id = blockIdx.x;
  int tm, tn, z;
  if(MODE==2){
    z = id & 1;
    int rid = id >> 1;
    tn = rid & 7;
    tm = rid >> 3;
  } else {
    int cpx = (int)gridDim.x >> 3;        // gridDim.x % 8 == 0 guaranteed
    int swz = (id & 7)*cpx + (id >> 3);
    tm = swz & 15; tn = swz >> 4;
    z = (int)blockIdx.z;
  }
  int kbase = z * (NT*64);
  const unsigned short* Ab = A  + (size_t)tm*256*K + kbase;
  const unsigned short* Bb = Bt + (size_t)tn*256*K + kbase;
  if(MODE!=0) Cf += (size_t)z * zstride;

  const int r0 = tid>>3;
  const int colc = ((tid&7) ^ (r0&7))*8;  // pre-swizzled global chunk
  const int dstw = wave*512;

#define STAGE(t_, h_, isB_) do{ \
    const unsigned short* g_ = (isB_) ? Bb : Ab; \
    int db_ = (((t_)&1)<<15) + ((isB_)<<14) + ((h_)<<13) + dstw; \
    gld_lds16(g_ + (size_t)((h_)*128 + r0)*K + (t_)*64 + colc, &lds[db_]); \
    gld_lds16(g_ + (size_t)((h_)*128 + r0 + 64)*K + (t_)*64 + colc, &lds[db_ + 4096]); \
  }while(0)

  const int sw8 = l15&7;
  const int fo0 = ((l4    )^sw8)*8;   // k-half 0
  const int fo1 = ((l4 + 4)^sw8)*8;   // k-half 1
  const int albase = (wr*128 + l15)*64;
  const int blbase = 16384 + (wc*64 + l15)*64;

#define RD_A4(arr_, buf_, mh_, fo_) do{ \
  _Pragma("unroll") for(int mf=0; mf<4; mf++) \
    arr_[mf] = *(const short8*)&lds[(buf_) + albase + (mh_)*4096 + mf*1024 + (fo_)]; }while(0)
#define RD_B4(arr_, buf_, fo_) do{ \
  _Pragma("unroll") for(int nf=0; nf<4; nf++) \
    arr_[nf] = *(const short8*)&lds[(buf_) + blbase + nf*1024 + (fo_)]; }while(0)
#define MFMA_P(aarr_, barr_, mh_) do{ \
  _Pragma("unroll") for(int mf=0; mf<4; mf++) \
  _Pragma("unroll") for(int nf=0; nf<4; nf++) \
    acc[(mh_)*4+mf][nf] = __builtin_amdgcn_mfma_f32_16x16x32_bf16( \
      aarr_[mf], barr_[nf], acc[(mh_)*4+mf][nf], 0,0,0); }while(0)

  floatx4 acc[8][4];
#pragma unroll
  for(int i=0;i<8;i++)
#pragma unroll
    for(int j=0;j<4;j++) acc[i][j] = (floatx4)0.f;

  STAGE(0,0,0); STAGE(0,1,0); STAGE(0,0,1); STAGE(0,1,1);
  STAGE(1,0,1); STAGE(1,1,1); STAGE(1,0,0);
  asm volatile("s_waitcnt vmcnt(6)" ::: "memory");
  BARR();

  short8 a00_[4], a01_[4], a10_[4], a11_[4], b0_[4], b1_[4];
  for(int t=0; t<NT; ++t){
    const int bufo = (t&1)<<15;
    // ---- P1 (m0,k0): reads a00+b0; stage A-h1(t+1); MFMA; BAR ----
    RD_A4(a00_, bufo, 0, fo0);
    RD_B4(b0_,  bufo, fo0);
    if(t+1 < NT) STAGE(t+1,1,0);
    __builtin_amdgcn_s_setprio(1);
    MFMA_P(a00_, b0_, 0);
    __builtin_amdgcn_s_setprio(0);
    BARR();
    // ---- P2 (m0,k1): reads a01+b1; stage B-h0(t+2); MFMA; BAR ----
    RD_A4(a01_, bufo, 0, fo1);
    RD_B4(b1_,  bufo, fo1);
    if(t+2 < NT) STAGE(t+2,0,1);
    __builtin_amdgcn_s_setprio(1);
    MFMA_P(a01_, b1_, 0);
    __builtin_amdgcn_s_setprio(0);
    BARR();
    // ---- P3 (m1,k0): reads a10, b0 reused; stage B-h1(t+2); MFMA; BAR ----
    RD_A4(a10_, bufo, 1, fo0);
    if(t+2 < NT) STAGE(t+2,1,1);
    __builtin_amdgcn_s_setprio(1);
    MFMA_P(a10_, b0_, 1);
    __builtin_amdgcn_s_setprio(0);
    BARR();
    // ---- P4 (m1,k1): reads a11, b1 reused; stage A-h0(t+2); vmcnt gate; MFMA; BAR ----
    RD_A4(a11_, bufo, 1, fo1);
    if(t+2 < NT){
      STAGE(t+2,0,0);
      asm volatile("s_waitcnt vmcnt(6)" ::: "memory");
    } else if(t+1 < NT){
      asm volatile("s_waitcnt vmcnt(0)" ::: "memory");
    }
    __builtin_amdgcn_s_setprio(1);
    MFMA_P(a11_, b1_, 1);
    __builtin_amdgcn_s_setprio(0);
    BARR();
  }

#pragma unroll
  for(int m=0;m<8;m++){
#pragma unroll
    for(int n=0;n<4;n++){
#pragma unroll
      for(int r=0;r<4;r++){
        size_t row = (size_t)tm*256 + wr*128 + (m>>2)*64 + (m&3)*16 + l4*4 + r;
        size_t col = (size_t)tn*256 + wc*64 + n*16 + l15;
        float v = acc[m][n][r];
        if(MODE==0)      Cb[row*N + col] = f2b(v);
        else             Cf[row*N + col] = v;
      }
    }
  }
}

// ---------------- partial sum: out = p0 + p1 (f32, float4) ----------------
__global__ __launch_bounds__(256) void add2_kernel(const float* __restrict__ p0,
                                                   const float* __restrict__ p1,
                                                   float* __restrict__ o, int n4){
  for(int i = blockIdx.x*256 + threadIdx.x; i < n4; i += gridDim.x*256){
    floatx4 a = ((const floatx4*)p0)[i];
    floatx4 b = ((const floatx4*)p1)[i];
    ((floatx4*)o)[i] = a + b;
  }
}

// ---------- flash causal attention, QBLK=128, 8 waves, K/V double-buffered (MQA) ----------
__global__ __launch_bounds__(512) void attn_kernel(const unsigned short* __restrict__ proj,
                                                   const unsigned short* __restrict__ vt,
                                                   unsigned short* __restrict__ ao){
  __shared__ unsigned short lK[2*8192];   // 2 x 16KB [key][d] chunk-swizzled
  __shared__ unsigned short lV[2*8192];   // 2 x 16KB [d][key] chunk-swizzled
  __shared__ unsigned short lP[8*1024];   // 16KB per-wave P
  int qt = (int)gridDim.x - 1 - (int)blockIdx.x;
  int hh = blockIdx.y, b = blockIdx.z;
  int tid = threadIdx.x, wave = tid>>6, lane = tid&63;
  int l15 = lane&15, l4 = lane>>4;
  int q0 = qt*128;
  int qrow = q0 + wave*16 + l15;
  const unsigned short* qp = proj + (size_t)(b*2048 + qrow)*FOUT + hh*128 + l4*8;
  short8 qf[4];
#pragma unroll
  for(int ds=0; ds<4; ds++) qf[ds] = *(const short8*)(qp + ds*32);
  floatx4 po[8];
#pragma unroll
  for(int dt=0; dt<8; dt++) po[dt] = (floatx4)0.f;
  float mrun[4] = {-1e30f,-1e30f,-1e30f,-1e30f};
  float lrun[4] = {0.f,0.f,0.f,0.f};
  unsigned short* lPw = lP + wave*1024;
  const unsigned short* kb = proj + (size_t)(b*2048)*FOUT + 2048;
  const unsigned short* vb = vt + (size_t)b*128*2048;
  int kvmax = 2*qt + 1;

#define STAGE_K(kv_, bo_) do{ \
    _Pragma("unroll") for(int it=0; it<2; it++){ \
      int f = it*512 + tid; \
      int r = f>>4, pc = f&15; \
      int gc = pc ^ (r&7); \
      gld_lds16(kb + (size_t)((kv_)*64 + r)*FOUT + gc*8, &lK[(bo_) + (it*512 + wave*64)*8]); \
    } }while(0)
#define STAGE_V(kv_, bo_) do{ \
    _Pragma("unroll") for(int it=0; it<2; it++){ \
      int f = it*512 + tid; \
      int d = f>>3, pc = f&7; \
      int gc = pc ^ (d&7); \
      gld_lds16(vb + (size_t)d*2048 + (kv_)*64 + gc*8, &lV[(bo_) + (it*512 + wave*64)*8]); \
    } }while(0)

  STAGE_K(0, 0); STAGE_V(0, 0);

  for(int kv=0; kv<=kvmax; kv++){
    int kv0 = kv*64;
    int cb = (kv&1)*8192;
    asm volatile("s_waitcnt vmcnt(0)" ::: "memory");
    __syncthreads();
    if(kv < kvmax){ STAGE_K(kv+1, cb^8192); STAGE_V(kv+1, cb^8192); }
    floatx4 sa[4];
#pragma unroll
    for(int jt=0;jt<4;jt++) sa[jt] = (floatx4)0.f;
#pragma unroll
    for(int jt=0;jt<4;jt++){
      int krow = jt*16 + l15;
#pragma unroll
      for(int ds=0; ds<4; ds++){
        int pc = (l4 + ds*4) ^ (krow&7);
        short8 kf = *(const short8*)&lK[cb + krow*128 + pc*8];
        sa[jt] = __builtin_amdgcn_mfma_f32_16x16x32_bf16(qf[ds], kf, sa[jt], 0,0,0);
      }
    }
    float pv[4][4];
    bool diag = (kv0 + 63 > q0 + wave*16);
#pragma unroll
    for(int jt=0;jt<4;jt++){
#pragma unroll
      for(int r=0;r<4;r++){
        float s = sa[jt][r];
        if(diag && (kv0 + jt*16 + l15 > q0 + wave*16 + l4*4 + r)) s = -1e30f;
        pv[jt][r] = s;
      }
    }
    float mnew[4], corr[4];
#pragma unroll
    for(int r=0;r<4;r++){
      float mx = fmaxf(fmaxf(pv[0][r],pv[1][r]),fmaxf(pv[2][r],pv[3][r]));
      mx = fmaxf(mx, __shfl_xor(mx, 1, 64));
      mx = fmaxf(mx, __shfl_xor(mx, 2, 64));
      mx = fmaxf(mx, __shfl_xor(mx, 4, 64));
      mx = fmaxf(mx, __shfl_xor(mx, 8, 64));
      float mn = fmaxf(mrun[r], mx);
      corr[r] = __expf(mrun[r] - mn);
      mrun[r] = mn;
      mnew[r] = mn;
    }
    float rsum[4] = {0.f,0.f,0.f,0.f};
#pragma unroll
    for(int jt=0;jt<4;jt++){
#pragma unroll
      for(int r=0;r<4;r++){
        float p = __expf(pv[jt][r] - mnew[r]);
        pv[jt][r] = p;
        rsum[r] += p;
      }
    }
#pragma unroll
    for(int r=0;r<4;r++){
      float rs = rsum[r];
      rs += __shfl_xor(rs, 1, 64);
      rs += __shfl_xor(rs, 2, 64);
      rs += __shfl_xor(rs, 4, 64);
      rs += __shfl_xor(rs, 8, 64);
      lrun[r] = lrun[r]*corr[r] + rs;
    }
#pragma unroll
    for(int dt=0;dt<8;dt++){
#pragma unroll
      for(int r=0;r<4;r++) po[dt][r] *= corr[r];
    }
#pragma unroll
    for(int jt=0;jt<4;jt++){
#pragma unroll
      for(int r=0;r<4;r++){
        int i_ = l4*4 + r;
        int j = jt*16 + l15;
        int pc = (j>>3) ^ (i_&7);
        lPw[i_*64 + pc*8 + (j&7)] = f2b(pv[jt][r]);
      }
    }
    asm volatile("s_waitcnt lgkmcnt(0)" ::: "memory");
    short8 pf[2];
#pragma unroll
    for(int ks=0;ks<2;ks++){
      int pc = (l4 + ks*4) ^ (l15&7);
      pf[ks] = *(const short8*)&lPw[l15*64 + pc*8];
    }
#pragma unroll
    for(int dt=0;dt<8;dt++){
      int d = dt*16 + l15;
#pragma unroll
      for(int ks=0;ks<2;ks++){
        int pc = (ks*4 + l4) ^ (d&7);
        short8 vf = *(const short8*)&lV[cb + d*64 + pc*8];
        po[dt] = __builtin_amdgcn_mfma_f32_16x16x32_bf16(pf[ks], vf, po[dt], 0,0,0);
      }
    }
  }
#pragma unroll
  for(int r=0;r<4;r++){
    float inv = 1.f / lrun[r];
    size_t orow = (size_t)(b*2048 + q0 + wave*16 + l4*4 + r);
#pragma unroll
    for(int dt=0;dt<8;dt++){
      ao[orow*CATW + hh*128 + dt*16 + l15] = f2b(po[dt][r]*inv);
    }
  }
}

// ---------------- SwiGLU: silu(gate)*x -> cat[:, 2048:10240] ----------------
__global__ __launch_bounds__(256) void swiglu_kernel(const unsigned short* __restrict__ proj,
                                                     unsigned short* __restrict__ cat){
  size_t idx = (size_t)blockIdx.x*256 + threadIdx.x;
  int row = (int)(idx >> 10);
  int c8  = (int)(idx & 1023);
  const unsigned short* pr = proj + (size_t)row*FOUT + 2304 + c8*8;
  ushort8 xv = *(const ushort8*)pr;
  ushort8 gv = *(const ushort8*)(pr + FFI);
  ushort8 ov;
#pragma unroll
  for(int e=0;e<8;e++){
    float xf = b2f(xv[e]);
    float gf = b2f(gv[e]);
    float sg = gf / (1.f + __expf(-gf));
    ov[e] = f2b(sg*xf);
  }
  *(ushort8*)(cat + (size_t)row*CATW + 2048 + c8*8) = ov;
}

extern "C" void kernel_launch(void* const* d_in, const int* in_sizes, int n_in,
                              void* d_out, int out_size, void* d_ws, size_t ws_size,
                              hipStream_t stream){
  const float* x     = (const float*)d_in[0];
  const float* gamma = (const float*)d_in[1];
  const float* Wf    = (const float*)d_in[2];
  const float* Wa    = (const float*)d_in[3];
  const float* Wff   = (const float*)d_in[4];
  float* out = (float*)d_out;

  char* p = (char*)d_ws;
  unsigned short* xn    = (unsigned short*)p;  p += (size_t)4096*2048*2;
  unsigned short* WfT   = (unsigned short*)p;  p += (size_t)18688*2048*2;
  unsigned short* proj  = (unsigned short*)p;  p += (size_t)4096*18688*2;
  unsigned short* BtCat = (unsigned short*)p;  p += (size_t)2048*CATW*2;
  unsigned short* cat   = (unsigned short*)p;  p += (size_t)4096*CATW*2;
  unsigned short* vtb   = (unsigned short*)p;  p += (size_t)2*128*2048*2;
  floatx4*        rtab  = (floatx4*)p;         p += (size_t)2048*64*16;
  float* part = (float*)d_ws;  // aliases xn+WfT (64 MB <= 92.5 MB, both dead by then)

  ln_kernel<<<4096, 256, 0, stream>>>(x, gamma, xn);
  rope_tab_kernel<<<512, 256, 0, stream>>>(rtab);
  tcast64_kernel<<<dim3(292,32),  256, 0, stream>>>(Wf,  WfT,   18688, 2048, 0);
  tcast64_kernel<<<dim3(32,32),   256, 0, stream>>>(Wa,  BtCat, 2048,  CATW, 0);
  tcast64_kernel<<<dim3(32,128),  256, 0, stream>>>(Wff, BtCat, 2048,  CATW, 2048);
  // GEMM1: proj = xn @ WfT^T   (4096 x 18688 x 2048), tn-major tiling
  gemm8p_kernel<0><<<dim3(1168,1,1), 512, 0, stream>>>(xn, WfT, proj, nullptr, 18688, 2048, 32, 0);
  rope_kernel<<<4096, 256, 0, stream>>>(proj, rtab);
  vtrans_kernel<<<dim3(64,4,2), dim3(32,8), 0, stream>>>(proj, vtb);
  attn_kernel<<<dim3(16,16,2), 512, 0, stream>>>(proj, vtb, cat);
  swiglu_kernel<<<16384, 256, 0, stream>>>(proj, cat);
  // GEMM23 fused: part[z] = cat[:, zK] @ BtCat[:, zK]^T  (4096 x 2048 x 10240, split-K=2,
  // z folded into x for per-XCD z coherence: even XCDs z=0, odd z=1)
  gemm8p_kernel<2><<<dim3(256,1,1), 512, 0, stream>>>(cat, BtCat, nullptr, part, 2048, 10240, 80,
                                                      (size_t)4096*2048);
  add2_kernel<<<2048, 256, 0, stream>>>(part, part + (size_t)4096*2048, out, 2097152);
}

// Round 19
// 714.579 us; speedup vs baseline: 1.1757x; 1.0074x over previous
//
#include <hip/hip_runtime.h>

typedef __attribute__((ext_vector_type(8))) short short8;
typedef __attribute__((ext_vector_type(4))) float floatx4;
typedef __attribute__((ext_vector_type(8))) unsigned short ushort8;

#define FOUT 18688
#define FFI  8192
#define CATW 10240   // 2048 (attn) + 8192 (swiglu)

__device__ __forceinline__ float b2f(unsigned short u){
  union { unsigned int i; float f; } v; v.i = ((unsigned int)u) << 16; return v.f;
}
__device__ __forceinline__ unsigned short f2b(float f){
  union { float f; unsigned int i; } v; v.f = f;
  unsigned int r = v.i + 0x7FFFu + ((v.i >> 16) & 1u);
  return (unsigned short)(r >> 16);
}
__device__ __forceinline__ void gld_lds16(const void* g, void* l){
  __builtin_amdgcn_global_load_lds((const __attribute__((address_space(1))) void*)g,
                                   (__attribute__((address_space(3))) void*)l, 16, 0, 0);
}

#define SCHED0() __builtin_amdgcn_sched_barrier(0)
#define BARR()   do{ SCHED0(); __builtin_amdgcn_s_barrier(); SCHED0(); }while(0)

// ---------------- LayerNorm (fp32 in) -> bf16 xn ----------------
__global__ __launch_bounds__(256) void ln_kernel(const float* __restrict__ x,
                                                 const float* __restrict__ gamma,
                                                 unsigned short* __restrict__ xn){
  int row = blockIdx.x;
  const float* xr = x + (size_t)row * 2048;
  int tid = threadIdx.x;
  float v[8]; float s = 0.f, s2 = 0.f;
#pragma unroll
  for(int i=0;i<8;i++){ float t = xr[tid + i*256]; v[i]=t; s+=t; s2+=t*t; }
#pragma unroll
  for(int off=32; off>=1; off>>=1){ s += __shfl_down(s, off, 64); s2 += __shfl_down(s2, off, 64); }
  __shared__ float red[8];
  int wv = tid>>6, ln_ = tid&63;
  if(ln_==0){ red[wv] = s; red[wv+4] = s2; }
  __syncthreads();
  s  = red[0]+red[1]+red[2]+red[3];
  s2 = red[4]+red[5]+red[6]+red[7];
  float mu  = s * (1.f/2048.f);
  float var = s2 * (1.f/2048.f) - mu*mu;
  float rstd = rsqrtf(var + 1e-5f);
#pragma unroll
  for(int i=0;i<8;i++){
    float o = (v[i]-mu)*rstd*gamma[tid + i*256];
    xn[(size_t)row*2048 + tid + i*256] = f2b(o);
  }
}

// ---------------- fp32 RxC -> bf16 CxR transpose, 64x64 tiles, vectorized ----------------
__global__ __launch_bounds__(256) void tcast64_kernel(const float* __restrict__ W,
                                                      unsigned short* __restrict__ Wt,
                                                      int C, int S, int O){
  __shared__ float t[64][65];
  int bx = blockIdx.x*64;   // col-block of W
  int by = blockIdx.y*64;   // row-block of W
  int tid = threadIdx.x;
  int r = tid>>2, cq = (tid&3)*16;
  const float* src = W + (size_t)(by + r)*C + bx + cq;
#pragma unroll
  for(int e=0;e<4;e++){
    floatx4 v = *(const floatx4*)(src + e*4);
    t[r][cq+e*4+0]=v[0]; t[r][cq+e*4+1]=v[1]; t[r][cq+e*4+2]=v[2]; t[r][cq+e*4+3]=v[3];
  }
  __syncthreads();
#pragma unroll
  for(int it=0; it<2; it++){
    int s_ = it*256 + tid;
    int c = s_>>3, j8 = s_&7;
    ushort8 o;
#pragma unroll
    for(int e=0;e<8;e++) o[e] = f2b(t[j8*8+e][c]);
    *(ushort8*)&Wt[(size_t)(bx+c)*S + O + by + j8*8] = o;
  }
}

// ---------------- V slice of proj -> Vt[b][d][n] (bf16) ----------------
__global__ void vtrans_kernel(const unsigned short* __restrict__ proj, unsigned short* __restrict__ vt){
  __shared__ unsigned short t[32][33];
  int b = blockIdx.z;
  int n0 = blockIdx.x*32, d0 = blockIdx.y*32;
  int tx = threadIdx.x, ty = threadIdx.y;
#pragma unroll
  for(int i=0;i<4;i++) t[ty+i*8][tx] = proj[(size_t)(b*2048 + n0+ty+i*8)*FOUT + 2176 + d0+tx];
  __syncthreads();
#pragma unroll
  for(int i=0;i<4;i++) vt[((size_t)b*128 + d0+ty+i*8)*2048 + n0+tx] = t[tx][ty+i*8];
}

// ---------------- RoPE table: [i<2048][j<64] {cq,sq,ck,sk}; att-scale folded into q ----------------
__global__ __launch_bounds__(256) void rope_tab_kernel(floatx4* __restrict__ tab){
  int idx = blockIdx.x*256 + threadIdx.x;   // 131072
  int i = idx >> 6, j = idx & 63;
  float fj = (float)j, fi = (float)i;
  float p = fi * powf(10000.f, -fj*(1.f/64.f));
  float c = cosf(p), s = sinf(p);
  float sv = (2.f*fj + 51.2f) * (1.f/179.2f);
  float pw = (fi - 1024.f) * (1.f/512.f);
  float sc = powf(sv, pw);
  const float att = 0.08838834764831843f;
  floatx4 o; o[0]=c*sc*att; o[1]=s*sc*att; o[2]=c/sc; o[3]=s/sc;
  tab[idx] = o;
}

// ---------------- RoPE (xpos) in-place on q heads + k, table-driven ----------------
__global__ __launch_bounds__(256) void rope_kernel(unsigned short* __restrict__ proj,
                                                   const floatx4* __restrict__ tab){
  int row = blockIdx.x;          // b*2048 + i
  int i = row & 2047;
  unsigned short* pr = proj + (size_t)row*FOUT;
  for(int item = threadIdx.x; item < 17*64; item += 256){
    int slot = item >> 6;        // 0..15 = q head, 16 = k
    int j = item & 63;
    floatx4 t = tab[i*64 + j];
    float cs = (slot==16) ? t[2] : t[0];
    float ss = (slot==16) ? t[3] : t[1];
    int colbase = (slot<16) ? slot*128 : 2048;
    float x1 = b2f(pr[colbase+j]);
    float x2 = b2f(pr[colbase+j+64]);
    pr[colbase+j]    = f2b(x1*cs - x2*ss);
    pr[colbase+j+64] = f2b(x2*cs + x1*ss);
  }
}

// ================= 256x256 bf16 GEMM — compiler-scheduled phases (R10-proven, 306us GEMM1) ===
// C(MxN) = A(MxK)*Bt(NxK)^T. BK=64, 8 waves (2M x 4N), 128KiB LDS dbuf.
// MODE 0: bf16 store, tn-major XCD tiling. MODE 1: f32 split-K partial via blockIdx.z.
// MODE 2: f32 split-K partial, z AND tm-group folded into XCD id: XCD=id&7 -> z=XCD&1,
//   tmg=XCD>>1 (each XCD: 4 tm x 8 tn, one z) -> per-XCD working set A 10.4MB + B 20.8MB
//   (was 42+5). tn=(id>>3)&7, tm=tmg*4+(id>>6). Bijective: id=64*tmL+8*tn+2*tmg+z.
template<int MODE>
__global__ __launch_bounds__(512, 2) void gemm8p_kernel(const unsigned short* __restrict__ A,
                                                        const unsigned short* __restrict__ Bt,
                                                        unsigned short* __restrict__ Cb,
                                                        float* __restrict__ Cf,
                                                        int N, int K, int NT, size_t zstride){
  __shared__ unsigned short lds[65536];   // [buf][A 16384 el | B 16384 el]
  const int tid = threadIdx.x;
  const int wave = tid>>6, lane = tid&63;
  const int l15 = lane&15, l4 = lane>>4;
  const int wr = wave>>2, wc = wave&3;    // 2(M) x 4(N)
  int id = blockIdx.x;
  int tm, tn, z;
  if(MODE==2){
    int x8 = id & 7;
    z  = x8 & 1;
    int tmg = x8 >> 1;
    tn = (id >> 3) & 7;
    tm = tmg*4 + (id >> 6);
  } else {
    int cpx = (int)gridDim.x >> 3;        // gridDim.x % 8 == 0 guaranteed
    int swz = (id & 7)*cpx + (id >> 3);
    tm = swz & 15; tn = swz >> 4;
    z = (int)blockIdx.z;
  }
  int kbase = z * (NT*64);
  const unsigned short* Ab = A  + (size_t)tm*256*K + kbase;
  const unsigned short* Bb = Bt + (size_t)tn*256*K + kbase;
  if(MODE!=0) Cf += (size_t)z * zstride;

  const int r0 = tid>>3;
  const int colc = ((tid&7) ^ (r0&7))*8;  // pre-swizzled global chunk
  const int dstw = wave*512;

#define STAGE(t_, h_, isB_) do{ \
    const unsigned short* g_ = (isB_) ? Bb : Ab; \
    int db_ = (((t_)&1)<<15) + ((isB_)<<14) + ((h_)<<13) + dstw; \
    gld_lds16(g_ + (size_t)((h_)*128 + r0)*K + (t_)*64 + colc, &lds[db_]); \
    gld_lds16(g_ + (size_t)((h_)*128 + r0 + 64)*K + (t_)*64 + colc, &lds[db_ + 4096]); \
  }while(0)

  const int sw8 = l15&7;
  const int fo0 = ((l4    )^sw8)*8;   // k-half 0
  const int fo1 = ((l4 + 4)^sw8)*8;   // k-half 1
  const int albase = (wr*128 + l15)*64;
  const int blbase = 16384 + (wc*64 + l15)*64;

#define RD_A4(arr_, buf_, mh_, fo_) do{ \
  _Pragma("unroll") for(int mf=0; mf<4; mf++) \
    arr_[mf] = *(const short8*)&lds[(buf_) + albase + (mh_)*4096 + mf*1024 + (fo_)]; }while(0)
#define RD_B4(arr_, buf_, fo_) do{ \
  _Pragma("unroll") for(int nf=0; nf<4; nf++) \
    arr_[nf] = *(const short8*)&lds[(buf_) + blbase + nf*1024 + (fo_)]; }while(0)
#define MFMA_P(aarr_, barr_, mh_) do{ \
  _Pragma("unroll") for(int mf=0; mf<4; mf++) \
  _Pragma("unroll") for(int nf=0; nf<4; nf++) \
    acc[(mh_)*4+mf][nf] = __builtin_amdgcn_mfma_f32_16x16x32_bf16( \
      aarr_[mf], barr_[nf], acc[(mh_)*4+mf][nf], 0,0,0); }while(0)

  floatx4 acc[8][4];
#pragma unroll
  for(int i=0;i<8;i++)
#pragma unroll
    for(int j=0;j<4;j++) acc[i][j] = (floatx4)0.f;

  STAGE(0,0,0); STAGE(0,1,0); STAGE(0,0,1); STAGE(0,1,1);
  STAGE(1,0,1); STAGE(1,1,1); STAGE(1,0,0);
  asm volatile("s_waitcnt vmcnt(6)" ::: "memory");
  BARR();

  short8 a00_[4], a01_[4], a10_[4], a11_[4], b0_[4], b1_[4];
  for(int t=0; t<NT; ++t){
    const int bufo = (t&1)<<15;
    // ---- P1 (m0,k0): reads a00+b0; stage A-h1(t+1); MFMA; BAR ----
    RD_A4(a00_, bufo, 0, fo0);
    RD_B4(b0_,  bufo, fo0);
    if(t+1 < NT) STAGE(t+1,1,0);
    __builtin_amdgcn_s_setprio(1);
    MFMA_P(a00_, b0_, 0);
    __builtin_amdgcn_s_setprio(0);
    BARR();
    // ---- P2 (m0,k1): reads a01+b1; stage B-h0(t+2); MFMA; BAR ----
    RD_A4(a01_, bufo, 0, fo1);
    RD_B4(b1_,  bufo, fo1);
    if(t+2 < NT) STAGE(t+2,0,1);
    __builtin_amdgcn_s_setprio(1);
    MFMA_P(a01_, b1_, 0);
    __builtin_amdgcn_s_setprio(0);
    BARR();
    // ---- P3 (m1,k0): reads a10, b0 reused; stage B-h1(t+2); MFMA; BAR ----
    RD_A4(a10_, bufo, 1, fo0);
    if(t+2 < NT) STAGE(t+2,1,1);
    __builtin_amdgcn_s_setprio(1);
    MFMA_P(a10_, b0_, 1);
    __builtin_amdgcn_s_setprio(0);
    BARR();
    // ---- P4 (m1,k1): reads a11, b1 reused; stage A-h0(t+2); vmcnt gate; MFMA; BAR ----
    RD_A4(a11_, bufo, 1, fo1);
    if(t+2 < NT){
      STAGE(t+2,0,0);
      asm volatile("s_waitcnt vmcnt(6)" ::: "memory");
    } else if(t+1 < NT){
      asm volatile("s_waitcnt vmcnt(0)" ::: "memory");
    }
    __builtin_amdgcn_s_setprio(1);
    MFMA_P(a11_, b1_, 1);
    __builtin_amdgcn_s_setprio(0);
    BARR();
  }

#pragma unroll
  for(int m=0;m<8;m++){
#pragma unroll
    for(int n=0;n<4;n++){
#pragma unroll
      for(int r=0;r<4;r++){
        size_t row = (size_t)tm*256 + wr*128 + (m>>2)*64 + (m&3)*16 + l4*4 + r;
        size_t col = (size_t)tn*256 + wc*64 + n*16 + l15;
        float v = acc[m][n][r];
        if(MODE==0)      Cb[row*N + col] = f2b(v);
        else             Cf[row*N + col] = v;
      }
    }
  }
}

// ---------------- partial sum: out = p0 + p1 (f32, float4) ----------------
__global__ __launch_bounds__(256) void add2_kernel(const float* __restrict__ p0,
                                                   const float* __restrict__ p1,
                                                   float* __restrict__ o, int n4){
  for(int i = blockIdx.x*256 + threadIdx.x; i < n4; i += gridDim.x*256){
    floatx4 a = ((const floatx4*)p0)[i];
    floatx4 b = ((const floatx4*)p1)[i];
    ((floatx4*)o)[i] = a + b;
  }
}

// ---------- flash causal attention, QBLK=128, 8 waves, K/V double-buffered (MQA) ----------
__global__ __launch_bounds__(512) void attn_kernel(const unsigned short* __restrict__ proj,
                                                   const unsigned short* __restrict__ vt,
                                                   unsigned short* __restrict__ ao){
  __shared__ unsigned short lK[2*8192];   // 2 x 16KB [key][d] chunk-swizzled
  __shared__ unsigned short lV[2*8192];   // 2 x 16KB [d][key] chunk-swizzled
  __shared__ unsigned short lP[8*1024];   // 16KB per-wave P
  int qt = (int)gridDim.x - 1 - (int)blockIdx.x;
  int hh = blockIdx.y, b = blockIdx.z;
  int tid = threadIdx.x, wave = tid>>6, lane = tid&63;
  int l15 = lane&15, l4 = lane>>4;
  int q0 = qt*128;
  int qrow = q0 + wave*16 + l15;
  const unsigned short* qp = proj + (size_t)(b*2048 + qrow)*FOUT + hh*128 + l4*8;
  short8 qf[4];
#pragma unroll
  for(int ds=0; ds<4; ds++) qf[ds] = *(const short8*)(qp + ds*32);
  floatx4 po[8];
#pragma unroll
  for(int dt=0; dt<8; dt++) po[dt] = (floatx4)0.f;
  float mrun[4] = {-1e30f,-1e30f,-1e30f,-1e30f};
  float lrun[4] = {0.f,0.f,0.f,0.f};
  unsigned short* lPw = lP + wave*1024;
  const unsigned short* kb = proj + (size_t)(b*2048)*FOUT + 2048;
  const unsigned short* vb = vt + (size_t)b*128*2048;
  int kvmax = 2*qt + 1;

#define STAGE_K(kv_, bo_) do{ \
    _Pragma("unroll") for(int it=0; it<2; it++){ \
      int f = it*512 + tid; \
      int r = f>>4, pc = f&15; \
      int gc = pc ^ (r&7); \
      gld_lds16(kb + (size_t)((kv_)*64 + r)*FOUT + gc*8, &lK[(bo_) + (it*512 + wave*64)*8]); \
    } }while(0)
#define STAGE_V(kv_, bo_) do{ \
    _Pragma("unroll") for(int it=0; it<2; it++){ \
      int f = it*512 + tid; \
      int d = f>>3, pc = f&7; \
      int gc = pc ^ (d&7); \
      gld_lds16(vb + (size_t)d*2048 + (kv_)*64 + gc*8, &lV[(bo_) + (it*512 + wave*64)*8]); \
    } }while(0)

  STAGE_K(0, 0); STAGE_V(0, 0);

  for(int kv=0; kv<=kvmax; kv++){
    int kv0 = kv*64;
    int cb = (kv&1)*8192;
    asm volatile("s_waitcnt vmcnt(0)" ::: "memory");
    __syncthreads();
    if(kv < kvmax){ STAGE_K(kv+1, cb^8192); STAGE_V(kv+1, cb^8192); }
    floatx4 sa[4];
#pragma unroll
    for(int jt=0;jt<4;jt++) sa[jt] = (floatx4)0.f;
#pragma unroll
    for(int jt=0;jt<4;jt++){
      int krow = jt*16 + l15;
#pragma unroll
      for(int ds=0; ds<4; ds++){
        int pc = (l4 + ds*4) ^ (krow&7);
        short8 kf = *(const short8*)&lK[cb + krow*128 + pc*8];
        sa[jt] = __builtin_amdgcn_mfma_f32_16x16x32_bf16(qf[ds], kf, sa[jt], 0,0,0);
      }
    }
    float pv[4][4];
    bool diag = (kv0 + 63 > q0 + wave*16);
#pragma unroll
    for(int jt=0;jt<4;jt++){
#pragma unroll
      for(int r=0;r<4;r++){
        float s = sa[jt][r];
        if(diag && (kv0 + jt*16 + l15 > q0 + wave*16 + l4*4 + r)) s = -1e30f;
        pv[jt][r] = s;
      }
    }
    float mnew[4], corr[4];
#pragma unroll
    for(int r=0;r<4;r++){
      float mx = fmaxf(fmaxf(pv[0][r],pv[1][r]),fmaxf(pv[2][r],pv[3][r]));
      mx = fmaxf(mx, __shfl_xor(mx, 1, 64));
      mx = fmaxf(mx, __shfl_xor(mx, 2, 64));
      mx = fmaxf(mx, __shfl_xor(mx, 4, 64));
      mx = fmaxf(mx, __shfl_xor(mx, 8, 64));
      float mn = fmaxf(mrun[r], mx);
      corr[r] = __expf(mrun[r] - mn);
      mrun[r] = mn;
      mnew[r] = mn;
    }
    float rsum[4] = {0.f,0.f,0.f,0.f};
#pragma unroll
    for(int jt=0;jt<4;jt++){
#pragma unroll
      for(int r=0;r<4;r++){
        float p = __expf(pv[jt][r] - mnew[r]);
        pv[jt][r] = p;
        rsum[r] += p;
      }
    }
#pragma unroll
    for(int r=0;r<4;r++){
      float rs = rsum[r];
      rs += __shfl_xor(rs, 1, 64);
      rs += __shfl_xor(rs, 2, 64);
      rs += __shfl_xor(rs, 4, 64);
      rs += __shfl_xor(rs, 8, 64);
      lrun[r] = lrun[r]*corr[r] + rs;
    }
#pragma unroll
    for(int dt=0;dt<8;dt++){
#pragma unroll
      for(int r=0;r<4;r++) po[dt][r] *= corr[r];
    }
#pragma unroll
    for(int jt=0;jt<4;jt++){
#pragma unroll
      for(int r=0;r<4;r++){
        int i_ = l4*4 + r;
        int j = jt*16 + l15;
        int pc = (j>>3) ^ (i_&7);
        lPw[i_*64 + pc*8 + (j&7)] = f2b(pv[jt][r]);
      }
    }
    asm volatile("s_waitcnt lgkmcnt(0)" ::: "memory");
    short8 pf[2];
#pragma unroll
    for(int ks=0;ks<2;ks++){
      int pc = (l4 + ks*4) ^ (l15&7);
      pf[ks] = *(const short8*)&lPw[l15*64 + pc*8];
    }
#pragma unroll
    for(int dt=0;dt<8;dt++){
      int d = dt*16 + l15;
#pragma unroll
      for(int ks=0;ks<2;ks++){
        int pc = (ks*4 + l4) ^ (d&7);
        short8 vf = *(const short8*)&lV[cb + d*64 + pc*8];
        po[dt] = __builtin_amdgcn_mfma_f32_16x16x32_bf16(pf[ks], vf, po[dt], 0,0,0);
      }
    }
  }
#pragma unroll
  for(int r=0;r<4;r++){
    float inv = 1.f / lrun[r];
    size_t orow = (size_t)(b*2048 + q0 + wave*16 + l4*4 + r);
#pragma unroll
    for(int dt=0;dt<8;dt++){
      ao[orow*CATW + hh*128 + dt*16 + l15] = f2b(po[dt][r]*inv);
    }
  }
}

// ---------------- SwiGLU: silu(gate)*x -> cat[:, 2048:10240] ----------------
__global__ __launch_bounds__(256) void swiglu_kernel(const unsigned short* __restrict__ proj,
                                                     unsigned short* __restrict__ cat){
  size_t idx = (size_t)blockIdx.x*256 + threadIdx.x;
  int row = (int)(idx >> 10);
  int c8  = (int)(idx & 1023);
  const unsigned short* pr = proj + (size_t)row*FOUT + 2304 + c8*8;
  ushort8 xv = *(const ushort8*)pr;
  ushort8 gv = *(const ushort8*)(pr + FFI);
  ushort8 ov;
#pragma unroll
  for(int e=0;e<8;e++){
    float xf = b2f(xv[e]);
    float gf = b2f(gv[e]);
    float sg = gf / (1.f + __expf(-gf));
    ov[e] = f2b(sg*xf);
  }
  *(ushort8*)(cat + (size_t)row*CATW + 2048 + c8*8) = ov;
}

extern "C" void kernel_launch(void* const* d_in, const int* in_sizes, int n_in,
                              void* d_out, int out_size, void* d_ws, size_t ws_size,
                              hipStream_t stream){
  const float* x     = (const float*)d_in[0];
  const float* gamma = (const float*)d_in[1];
  const float* Wf    = (const float*)d_in[2];
  const float* Wa    = (const float*)d_in[3];
  const float* Wff   = (const float*)d_in[4];
  float* out = (float*)d_out;

  char* p = (char*)d_ws;
  unsigned short* xn    = (unsigned short*)p;  p += (size_t)4096*2048*2;
  unsigned short* WfT   = (unsigned short*)p;  p += (size_t)18688*2048*2;
  unsigned short* proj  = (unsigned short*)p;  p += (size_t)4096*18688*2;
  unsigned short* BtCat = (unsigned short*)p;  p += (size_t)2048*CATW*2;
  unsigned short* cat   = (unsigned short*)p;  p += (size_t)4096*CATW*2;
  unsigned short* vtb   = (unsigned short*)p;  p += (size_t)2*128*2048*2;
  floatx4*        rtab  = (floatx4*)p;         p += (size_t)2048*64*16;
  float* part = (float*)d_ws;  // aliases xn+WfT (64 MB <= 92.5 MB, both dead by then)

  ln_kernel<<<4096, 256, 0, stream>>>(x, gamma, xn);
  rope_tab_kernel<<<512, 256, 0, stream>>>(rtab);
  tcast64_kernel<<<dim3(292,32),  256, 0, stream>>>(Wf,  WfT,   18688, 2048, 0);
  tcast64_kernel<<<dim3(32,32),   256, 0, stream>>>(Wa,  BtCat, 2048,  CATW, 0);
  tcast64_kernel<<<dim3(32,128),  256, 0, stream>>>(Wff, BtCat, 2048,  CATW, 2048);
  // GEMM1: proj = xn @ WfT^T   (4096 x 18688 x 2048), tn-major tiling
  gemm8p_kernel<0><<<dim3(1168,1,1), 512, 0, stream>>>(xn, WfT, proj, nullptr, 18688, 2048, 32, 0);
  rope_kernel<<<4096, 256, 0, stream>>>(proj, rtab);
  vtrans_kernel<<<dim3(64,4,2), dim3(32,8), 0, stream>>>(proj, vtb);
  attn_kernel<<<dim3(16,16,2), 512, 0, stream>>>(proj, vtb, cat);
  swiglu_kernel<<<16384, 256, 0, stream>>>(proj, cat);
  // GEMM23 fused: part[z] = cat[:, zK] @ BtCat[:, zK]^T  (4096 x 2048 x 10240, split-K=2,
  // z + tm-group folded into XCD id: each XCD owns 4 tm x 8 tn of one z -> 31MB working set)
  gemm8p_kernel<2><<<dim3(256,1,1), 512, 0, stream>>>(cat, BtCat, nullptr, part, 2048, 10240, 80,
                                                      (size_t)4096*2048);
  add2_kernel<<<2048, 256, 0, stream>>>(part, part + (size_t)4096*2048, out, 2097152);
}